// Round 1
// baseline (70.298 us; speedup 1.0000x reference)
//
#include <hip/hip_runtime.h>
#include <hip/hip_bf16.h>

// Sliding-window causal attention, B=4, S=4096, d=64, window [i-256, i].
// Round 4: stage-everything-first, barrier-free inner loop.
//  - LDS 122 KiB: Q (64 rows) + ALL 5 K/V chunks (320 keys) staged before ONE
//    barrier; the 5-chunk compute loop then has no barriers at all (K/V are
//    read-only, P is wave-private -> lgkmcnt only). Barriers: 11 -> 2.
//  - All global loads issued up front (MLP), latency paid once.
//  - Same wave decomposition as round 3: 4 query-stripes x 2 key-groups with
//    end merge; DPP 16-lane softmax reductions.
// Layouts (HW-verified per guide §3): A[m=lane&15][k=quad*8+j];
// C/D col=lane&15, row=quad*4+reg.

#define LOG2E 1.4426950408889634f

typedef __attribute__((ext_vector_type(8))) short  frag;    // 8 bf16
typedef __attribute__((ext_vector_type(4))) float  f32x4;   // C/D

static __device__ inline short f2bf(float x) {
    __hip_bfloat16 h = __float2bfloat16(x);   // RTNE
    return __builtin_bit_cast(short, h);
}

#define DPPF(x, ctrl) __builtin_bit_cast(float, \
    __builtin_amdgcn_mov_dpp(__builtin_bit_cast(int, (x)), (ctrl), 0xF, 0xF, true))

static __device__ inline float red16_max(float x) {
    x = fmaxf(x, DPPF(x, 0xB1));   // quad_perm xor 1
    x = fmaxf(x, DPPF(x, 0x4E));   // quad_perm xor 2
    x = fmaxf(x, DPPF(x, 0x141));  // row_half_mirror (~xor 4)
    x = fmaxf(x, DPPF(x, 0x140));  // row_mirror      (~xor 8)
    return x;
}
static __device__ inline float red16_sum(float x) {
    x += DPPF(x, 0xB1);
    x += DPPF(x, 0x4E);
    x += DPPF(x, 0x141);
    x += DPPF(x, 0x140);
    return x;
}

#define LSTR 72    // Q/K LDS row stride (bf16), 144 B -> 16B-aligned rows
#define VSTR 328   // Vt row stride (bf16): 320 keys + 8 pad, 656 B rows
#define PSTR 40    // P tile row stride (16 x 32 keys + pad)
#define OSTR 65    // merge buffer row stride (fp32)

__global__ __launch_bounds__(512, 2) void swa_mfma3(const float* __restrict__ qkv,
                                                    float* __restrict__ out)
{
    __shared__ short Qs[64 * LSTR];        //  9216 B
    __shared__ short Ks[320 * LSTR];       // 46080 B  (all 5 chunks)
    __shared__ short Vt[64 * VSTR];        // 41984 B  Vt[dim][key], all chunks
    __shared__ short Pw[8][16 * PSTR];     // 10240 B  per-wave P
    __shared__ float Om[4][16 * OSTR];     // 16640 B  group-1 O partials
    __shared__ float2 mlbuf[4][16];        //   512 B
    // total ~124.7 KB (<128 KiB precedent, <160 KiB HW) -> 1 block/CU

    const int b    = blockIdx.y;
    const int q0   = blockIdx.x * 64;
    const int t    = threadIdx.x;
    const int w    = t >> 6;        // 0..7
    const int s    = w & 3;         // query stripe: rows 16s..16s+15
    const int g    = w >> 2;        // key group: tiles {2g, 2g+1} per chunk
    const int lane = t & 63;
    const int cl   = lane & 15;
    const int quad = lane >> 4;
    const int ql   = 4 * quad;

    const float4* qkv4 = (const float4*)qkv;   // 48 float4 per (b,seq) row
    const int r_st = t >> 3;        // staging row 0..63
    const int c8   = t & 7;         // staging float4-col (two: c8, c8+8)

    const int c0 = (q0 >= 256) ? 0 : (4 - (q0 >> 6));

    // ---- stage Q (x 1/8 scale folded in) ----
    {
        const size_t base = (size_t)(b * 4096 + q0 + r_st) * 48;
        #pragma unroll
        for (int i = 0; i < 2; ++i) {
            float4 v = qkv4[base + c8 + 8 * i];
            short4 s4 = { f2bf(v.x * 0.125f), f2bf(v.y * 0.125f),
                          f2bf(v.z * 0.125f), f2bf(v.w * 0.125f) };
            *(short4*)&Qs[r_st * LSTR + 4 * (c8 + 8 * i)] = s4;
        }
    }

    // ---- stage ALL K/V chunks (unrolled: static indexing, loads batch up) ----
    const int kbase = b * 4096 + q0 - 256;
    #pragma unroll
    for (int c = 0; c < 5; ++c) {
        if (c < c0) continue;                       // block-uniform branch
        const size_t base = (size_t)(kbase + 64 * c + r_st) * 48;
        #pragma unroll
        for (int i = 0; i < 2; ++i) {
            float4 kv = qkv4[base + 16 + c8 + 8 * i];
            float4 vv = qkv4[base + 32 + c8 + 8 * i];
            short4 k4 = { f2bf(kv.x), f2bf(kv.y), f2bf(kv.z), f2bf(kv.w) };
            *(short4*)&Ks[(64 * c + r_st) * LSTR + 4 * (c8 + 8 * i)] = k4;
            const int d0 = 4 * (c8 + 8 * i);
            Vt[(d0 + 0) * VSTR + 64 * c + r_st] = f2bf(vv.x);
            Vt[(d0 + 1) * VSTR + 64 * c + r_st] = f2bf(vv.y);
            Vt[(d0 + 2) * VSTR + 64 * c + r_st] = f2bf(vv.z);
            Vt[(d0 + 3) * VSTR + 64 * c + r_st] = f2bf(vv.w);
        }
    }

    __syncthreads();   // ONE barrier: everything staged

    const frag qf0 = *(const frag*)&Qs[(16 * s + cl) * LSTR + 8 * quad];
    const frag qf1 = *(const frag*)&Qs[(16 * s + cl) * LSTR + 32 + 8 * quad];

    float m[4], l[4];
    f32x4 oacc[4];
    #pragma unroll
    for (int r = 0; r < 4; ++r) { m[r] = -1e30f; l[r] = 0.f; }
    #pragma unroll
    for (int n4 = 0; n4 < 4; ++n4) oacc[n4] = (f32x4){0.f, 0.f, 0.f, 0.f};

    // ---- barrier-free flash loop over the 5 chunks ----
    #pragma unroll
    for (int c = 0; c < 5; ++c) {
        if (c < c0) continue;

        // S = Q K^T over this group's 2 key-tiles of chunk c
        f32x4 sc[2];
        #pragma unroll
        for (int u = 0; u < 2; ++u) {
            const int t4 = 2 * g + u;
            const int krow = 64 * c + 16 * t4;
            sc[u] = (f32x4){0.f, 0.f, 0.f, 0.f};
            const frag kf0 = *(const frag*)&Ks[(krow + cl) * LSTR + 8 * quad];
            const frag kf1 = *(const frag*)&Ks[(krow + cl) * LSTR + 32 + 8 * quad];
            sc[u] = __builtin_amdgcn_mfma_f32_16x16x32_bf16(qf0, kf0, sc[u], 0, 0, 0);
            sc[u] = __builtin_amdgcn_mfma_f32_16x16x32_bf16(qf1, kf1, sc[u], 0, 0, 0);
        }

        // sliding-window mask (edge chunks only)
        if (c == 4) {           // causal: keep key <= query
            #pragma unroll
            for (int u = 0; u < 2; ++u) {
                const int t4 = 2 * g + u;
                #pragma unroll
                for (int r = 0; r < 4; ++r)
                    if (16 * s + ql + r < 16 * t4 + cl) sc[u][r] = -1e30f;
            }
        } else if (c == 0) {    // left edge (only runs when q0 >= 256)
            #pragma unroll
            for (int u = 0; u < 2; ++u) {
                const int t4 = 2 * g + u;
                #pragma unroll
                for (int r = 0; r < 4; ++r)
                    if (16 * s + ql + r > 16 * t4 + cl) sc[u][r] = -1e30f;
            }
        }

        // online softmax (DPP 16-lane reductions)
        #pragma unroll
        for (int r = 0; r < 4; ++r) {
            float mx = red16_max(fmaxf(sc[0][r], sc[1][r]));
            const float mnew  = fmaxf(m[r], mx);
            const float alpha = __builtin_amdgcn_exp2f((m[r] - mnew) * LOG2E);
            m[r] = mnew;
            float sum = 0.f;
            #pragma unroll
            for (int u = 0; u < 2; ++u) {
                float p = (sc[u][r] <= -1e29f)
                            ? 0.f
                            : __builtin_amdgcn_exp2f((sc[u][r] - mnew) * LOG2E);
                Pw[w][(ql + r) * PSTR + 16 * u + cl] = f2bf(p);
                sum += p;
            }
            l[r] = l[r] * alpha + red16_sum(sum);
            #pragma unroll
            for (int n4 = 0; n4 < 4; ++n4) oacc[n4][r] *= alpha;
        }

        // O += P V   (P wave-private: lgkmcnt only, no barrier)
        const frag pf = *(const frag*)&Pw[w][cl * PSTR + 8 * quad];
        #pragma unroll
        for (int n4 = 0; n4 < 4; ++n4) {
            const frag vf = *(const frag*)&Vt[(16 * n4 + cl) * VSTR + 64 * c + 32 * g + 8 * quad];
            oacc[n4] = __builtin_amdgcn_mfma_f32_16x16x32_bf16(pf, vf, oacc[n4], 0, 0, 0);
        }
    }

    // ---- merge the two key-groups per stripe ----
    if (g == 1) {
        #pragma unroll
        for (int n4 = 0; n4 < 4; ++n4)
            #pragma unroll
            for (int r = 0; r < 4; ++r)
                Om[s][(ql + r) * OSTR + 16 * n4 + cl] = oacc[n4][r];
        if (cl == 0)
            #pragma unroll
            for (int r = 0; r < 4; ++r)
                mlbuf[s][ql + r] = make_float2(m[r], l[r]);
    }
    __syncthreads();
    if (g == 0) {
        #pragma unroll
        for (int r = 0; r < 4; ++r) {
            const float2 ml1 = mlbuf[s][ql + r];
            const float M  = fmaxf(m[r], ml1.x);
            const float a0 = __builtin_amdgcn_exp2f((m[r]  - M) * LOG2E);
            const float a1 = __builtin_amdgcn_exp2f((ml1.x - M) * LOG2E);
            const float L  = l[r] * a0 + ml1.y * a1;
            const float inv = 1.0f / L;
            const size_t row = (size_t)(b * 4096 + q0 + 16 * s + ql + r) * 64;
            #pragma unroll
            for (int n4 = 0; n4 < 4; ++n4) {
                const float o1 = Om[s][(ql + r) * OSTR + 16 * n4 + cl];
                out[row + 16 * n4 + cl] = (oacc[n4][r] * a0 + o1 * a1) * inv;
            }
        }
    }
}

extern "C" void kernel_launch(void* const* d_in, const int* in_sizes, int n_in,
                              void* d_out, int out_size, void* d_ws, size_t ws_size,
                              hipStream_t stream) {
    const float* qkv = (const float*)d_in[0];
    float* out = (float*)d_out;
    dim3 grid(64, 4);
    dim3 block(512);
    hipLaunchKernelGGL(swa_mfma3, grid, block, 0, stream, qkv, out);
}